// Round 9
// baseline (156.664 us; speedup 1.0000x reference)
//
#include <hip/hip_runtime.h>
#include <hip/hip_bf16.h>
#include <math.h>

#define NN 131072
#define BSEG 16
#define CCH 128
#define KK 16
#define EPSF 1e-9f
#define XST 136   // LDS row stride in bf16 elements (128 + 8 pad, 16B aligned)

// d_out layout (floats): out[B*K*C]=32768 | s[N*K]=2097152 | mu[B*K*2]=512 | losses[9]
#define OFF_S   32768
#define OFF_MU  2129920
#define OFF_L   2130432

// ws layout (floats):
//  [0]                       is64 flag
//  [REDC_BASE .. +64*1024)   64 staged copies of the small-reduction block:
//                            addr 0..255 sum_s[seg*16+k], 256..767 sum_pos[seg*32+2k+d], 768 ent
//  [ST_BASE .. +8*32768)     8 staged copies of out accumulator (atomics, blockIdx&7)
#define REDC_BASE 1024
#define REDC_STRIDE 1024
#define NRED 64
#define ST_BASE (REDC_BASE + NRED * REDC_STRIDE)   // 66560
#define NST 8
#define ST_SZ (BSEG * KK * CCH)                    // 32768

#define TILES 2   // 128-node tiles per block; pooling acc carried in regs across tiles

typedef __bf16 bf16x8 __attribute__((ext_vector_type(8)));
typedef float  f32x4  __attribute__((ext_vector_type(4)));
typedef float  f32x16 __attribute__((ext_vector_type(16)));

__device__ __forceinline__ int load_batch(const void* bptr, int n, int is64) {
    if (is64) return (int)((const long long*)bptr)[n];
    return ((const int*)bptr)[n];
}

__device__ __forceinline__ float wave_sum(float v) {
#pragma unroll
    for (int o = 32; o > 0; o >>= 1) v += __shfl_xor(v, o, 64);
    return v;
}

__device__ __forceinline__ bf16x8 pack8(float4 a, float4 b) {
    bf16x8 v;
    v[0] = (__bf16)a.x; v[1] = (__bf16)a.y; v[2] = (__bf16)a.z; v[3] = (__bf16)a.w;
    v[4] = (__bf16)b.x; v[5] = (__bf16)b.y; v[6] = (__bf16)b.z; v[7] = (__bf16)b.w;
    return v;
}

__global__ void k_zero(float* __restrict__ ws, const int* __restrict__ b32) {
    int i = blockIdx.x * 256 + threadIdx.x;   // grid 1280*256 = 327680 == NRED*1024 + NST*ST_SZ
    ws[REDC_BASE + i] = 0.0f;
    if (i == 0) ws[0] = (b32[NN - 1] == 0) ? 1.0f : 0.0f;  // int64 high word at odd idx => 0
}

// R8 structure (TILES=2, hoisted W1, fused GEMM2+softmax, reg-carried pooling acc)
// + swapped-operand GEMM2: mfma(w2frag, hfrag, acc) transposes the output so each
// lane holds logits[k=g*4+r][node=lane&15] -> softmax max/sum need only 2 shfls
// (xor 16,32) per node instead of 4-shfl chains per value (96 -> 8 shfls/wave/tile).
// Entropy reduction deferred to one end-of-phase wave_sum. gumbel/s_out become
// float4 accesses. NST 4->8 halves stg atomic contention.
__global__ __launch_bounds__(256, 2) void k_fused(
    const float* __restrict__ x, const void* __restrict__ batch,
    const float* __restrict__ pos, const float* __restrict__ gumbel,
    const float* __restrict__ W1, const float* __restrict__ b1,
    const float* __restrict__ W2, const float* __restrict__ b2,
    const float* __restrict__ scaling, const float* __restrict__ active_mask,
    float* __restrict__ s_out, float* __restrict__ ws)
{
    __shared__ __align__(16) __bf16 x_lds[128 * XST];
    __shared__ __align__(16) __bf16 h_lds[128 * XST];
    __shared__ __align__(16) __bf16 sT[16 * XST];
    __shared__ float2 pos_lds[128];
    __shared__ int bsegs[128];

    const int tid  = threadIdx.x;
    const int lane = tid & 63;
    const int wv   = tid >> 6;          // [0,4)
    const int is64 = (int)ws[0];

    float* rc  = ws + REDC_BASE + (size_t)(blockIdx.x & (NRED - 1)) * REDC_STRIDE;
    float* stg = ws + ST_BASE   + (size_t)(blockIdx.x & (NST  - 1)) * ST_SZ;

    // ---- W1 fragment + bias, loaded ONCE per block (issues overlap tile-0 staging) ----
    bf16x8 bfr[8];
    {
        const float* wrow = W1 + (size_t)(wv * 32 + (lane & 31)) * CCH + (lane >> 5) * 8;
#pragma unroll
        for (int ks = 0; ks < 8; ks++) {
            float4 u = *(const float4*)(wrow + ks * 16);
            float4 v = *(const float4*)(wrow + ks * 16 + 4);
            bfr[ks] = pack8(u, v);
        }
    }
    const float b1j = b1[wv * 32 + (lane & 31)];

    // pooling accumulator carried ACROSS tiles (batch sorted => seg rarely changes)
    f32x4 pacc[2];
#pragma unroll
    for (int t = 0; t < 2; t++)
#pragma unroll
        for (int r = 0; r < 4; r++) pacc[t][r] = 0.0f;
    int curseg = -1;

    for (int t = 0; t < TILES; t++) {
        const int n0 = blockIdx.x * (TILES * 128) + t * 128;

        if (t) __syncthreads();   // previous tile's pooling must finish reading x_lds/sT/bsegs

        // ---- stage: batch+pos -> LDS, gumbel -> regs (float4), x -> LDS bf16 ----
        if (tid < 128) {
            bsegs[tid] = load_batch(batch, n0 + tid, is64);
            pos_lds[tid] = ((const float2*)pos)[n0 + tid];
        }
        // prefetch gumbel[node][g*4..g*4+4) for this lane's 2 nodes (coalesced f4)
        const int nd = lane & 15;       // node within 16-node tile
        const int g  = lane >> 4;       // k-group: k = g*4+r
        float4 gu[2];
        {
#pragma unroll
            for (int tt = 0; tt < 2; tt++) {
                int node = (wv * 2 + tt) * 16 + nd;
                gu[tt] = *(const float4*)(gumbel + (size_t)(n0 + node) * KK + g * 4);
            }
        }
        {
            const float4* xg = (const float4*)(x + (size_t)n0 * CCH);
#pragma unroll
            for (int i = 0; i < 8; i++) {
                int p = i * 256 + tid;          // pair of float4 = 8 elements
                float4 a = xg[2 * p], b = xg[2 * p + 1];
                *(bf16x8*)&x_lds[(p >> 4) * XST + (p & 15) * 8] = pack8(a, b);
            }
        }
        __syncthreads();

        // ================= GEMM1: h = relu(x @ W1^T + b1), 32x32x16 =================
        {
            f32x16 acc[4];
#pragma unroll
            for (int mt = 0; mt < 4; mt++)
#pragma unroll
                for (int r = 0; r < 16; r++) acc[mt][r] = 0.0f;

#pragma unroll
            for (int ks = 0; ks < 8; ks++) {
#pragma unroll
                for (int mt = 0; mt < 4; mt++) {
                    bf16x8 a = *(bf16x8*)&x_lds[(size_t)(mt * 32 + (lane & 31)) * XST + ks * 16 + (lane >> 5) * 8];
                    acc[mt] = __builtin_amdgcn_mfma_f32_32x32x16_bf16(a, bfr[ks], acc[mt], 0, 0, 0);
                }
            }
#pragma unroll
            for (int mt = 0; mt < 4; mt++)
#pragma unroll
                for (int r = 0; r < 16; r++) {
                    int node = mt * 32 + (r & 3) + 8 * (r >> 2) + 4 * (lane >> 5);
                    h_lds[(size_t)node * XST + wv * 32 + (lane & 31)] = (__bf16)fmaxf(acc[mt][r] + b1j, 0.0f);
                }
        }
        __syncthreads();

        // == fused: GEMM2 swapped (lane holds logits[k=g*4+r][node=nd]) + softmax ==
        {
            const int bf = bsegs[0], bl = bsegs[127];
            const float sc = scaling[0];
            float b2v[4], amv[4];
#pragma unroll
            for (int r = 0; r < 4; r++) { b2v[r] = b2[g * 4 + r]; amv[r] = active_mask[g * 4 + r]; }

            f32x4 acc2[2];
#pragma unroll
            for (int tt = 0; tt < 2; tt++)
#pragma unroll
                for (int r = 0; r < 4; r++) acc2[tt][r] = 0.0f;

#pragma unroll
            for (int ks = 0; ks < 4; ks++) {
                const float* w2row = W2 + (size_t)nd * CCH + ks * 32 + g * 8;   // W2[k=nd] as A-frag
                float4 u = *(const float4*)w2row;
                float4 v4 = *(const float4*)(w2row + 4);
                bf16x8 bwf = pack8(u, v4);
#pragma unroll
                for (int tt = 0; tt < 2; tt++) {
                    bf16x8 a = *(bf16x8*)&h_lds[(size_t)((wv * 2 + tt) * 16 + nd) * XST + ks * 32 + g * 8];
                    // SWAPPED: A = W2 fragment, B = h fragment -> D[k][node]
                    acc2[tt] = __builtin_amdgcn_mfma_f32_16x16x32_bf16(bwf, a, acc2[tt], 0, 0, 0);
                }
            }

            float sA[4] = {0, 0, 0, 0}, pxA[4] = {0, 0, 0, 0}, pyA[4] = {0, 0, 0, 0};
            float sB[4] = {0, 0, 0, 0}, pxB[4] = {0, 0, 0, 0}, pyB[4] = {0, 0, 0, 0};
            float entacc = 0.0f;
            const bool dual = (bf != bl);

#pragma unroll
            for (int tt = 0; tt < 2; tt++) {
                const int node = (wv * 2 + tt) * 16 + nd;
                float v[4];
#pragma unroll
                for (int r = 0; r < 4; r++) {
                    float vv = (acc2[tt][r] + b2v[r]) * sc;
                    if (amv[r] == 0.0f) vv = -1e9f;
                    v[r] = vv + ((const float*)&gu[tt])[r];   // TAU == 1.0
                }
                float vm = fmaxf(fmaxf(v[0], v[1]), fmaxf(v[2], v[3]));
                vm = fmaxf(vm, __shfl_xor(vm, 16, 64));
                vm = fmaxf(vm, __shfl_xor(vm, 32, 64));
                float e[4];
                float ls = 0.0f;
#pragma unroll
                for (int r = 0; r < 4; r++) { e[r] = expf(v[r] - vm); ls += e[r]; }
                ls += __shfl_xor(ls, 16, 64);
                ls += __shfl_xor(ls, 32, 64);
                const float inv = 1.0f / ls;
                float s[4];
#pragma unroll
                for (int r = 0; r < 4; r++) s[r] = e[r] * inv;

                // coalesced float4 store of this node's 4 k-values
                float4 so; so.x = s[0]; so.y = s[1]; so.z = s[2]; so.w = s[3];
                *(float4*)(s_out + (size_t)(n0 + node) * KK + g * 4) = so;
#pragma unroll
                for (int r = 0; r < 4; r++) sT[(g * 4 + r) * XST + node] = (__bf16)s[r];

#pragma unroll
                for (int r = 0; r < 4; r++) entacc += s[r] * logf(s[r] + EPSF);

                const float2 pp = pos_lds[node];
                const float w0 = (bsegs[node] == bf) ? 1.0f : 0.0f;
#pragma unroll
                for (int r = 0; r < 4; r++) {
                    const float sa = s[r] * w0;
                    sA[r] += sa; pxA[r] += sa * pp.x; pyA[r] += sa * pp.y;
                }
                if (dual) {
#pragma unroll
                    for (int r = 0; r < 4; r++) {
                        const float sb = s[r] * (1.0f - w0);
                        sB[r] += sb; pxB[r] += sb * pp.x; pyB[r] += sb * pp.y;
                    }
                }
            }

            // reduce over the 16 node-lanes (xor 1,2,4,8) for each of the 12 regs
#pragma unroll
            for (int o = 1; o < 16; o <<= 1) {
#pragma unroll
                for (int r = 0; r < 4; r++) {
                    sA[r]  += __shfl_xor(sA[r],  o, 64);
                    pxA[r] += __shfl_xor(pxA[r], o, 64);
                    pyA[r] += __shfl_xor(pyA[r], o, 64);
                }
            }
            if (nd == 0) {
#pragma unroll
                for (int r = 0; r < 4; r++) {
                    const int k = g * 4 + r;
                    atomicAdd(&rc[bf * 16 + k], sA[r]);
                    atomicAdd(&rc[256 + bf * 32 + 2 * k],     pxA[r]);
                    atomicAdd(&rc[256 + bf * 32 + 2 * k + 1], pyA[r]);
                }
            }
            if (dual) {
#pragma unroll
                for (int o = 1; o < 16; o <<= 1) {
#pragma unroll
                    for (int r = 0; r < 4; r++) {
                        sB[r]  += __shfl_xor(sB[r],  o, 64);
                        pxB[r] += __shfl_xor(pxB[r], o, 64);
                        pyB[r] += __shfl_xor(pyB[r], o, 64);
                    }
                }
                if (nd == 0) {
#pragma unroll
                    for (int r = 0; r < 4; r++) {
                        const int k = g * 4 + r;
                        atomicAdd(&rc[bl * 16 + k], sB[r]);
                        atomicAdd(&rc[256 + bl * 32 + 2 * k],     pxB[r]);
                        atomicAdd(&rc[256 + bl * 32 + 2 * k + 1], pyB[r]);
                    }
                }
            }
            float entw = wave_sum(entacc);
            if (lane == 0) atomicAdd(&rc[768], entw);
        }
        __syncthreads();

        // == pooling: pacc[tt][k,c] += s[n,k]*x[n,c] via 16x16x32; flush on seg change ==
        {
            const int bf = bsegs[0], bl = bsegs[127];
            const bool masked = (bf != bl);
            for (int seg = bf; seg <= bl; seg++) {
                if (seg != curseg) {
                    if (curseg >= 0) {
#pragma unroll
                        for (int tt = 0; tt < 2; tt++) {
#pragma unroll
                            for (int r = 0; r < 4; r++) {
                                int k = (lane >> 4) * 4 + r;
                                int c = (wv * 2 + tt) * 16 + (lane & 15);
                                atomicAdd(&stg[((size_t)curseg * KK + k) * CCH + c], pacc[tt][r]);
                            }
#pragma unroll
                            for (int r = 0; r < 4; r++) pacc[tt][r] = 0.0f;
                        }
                    }
                    curseg = seg;
                }
#pragma unroll
                for (int ks = 0; ks < 4; ks++) {
                    bf16x8 a = *(bf16x8*)&sT[(size_t)(lane & 15) * XST + ks * 32 + (lane >> 4) * 8];
                    if (masked) {
#pragma unroll
                        for (int i = 0; i < 8; i++) {
                            int ndd = ks * 32 + (lane >> 4) * 8 + i;
                            if (bsegs[ndd] != seg) a[i] = (__bf16)0.0f;
                        }
                    }
#pragma unroll
                    for (int tt = 0; tt < 2; tt++) {
                        int ct = wv * 2 + tt;
                        bf16x8 bx;
#pragma unroll
                        for (int i = 0; i < 8; i++)
                            bx[i] = x_lds[(size_t)(ks * 32 + (lane >> 4) * 8 + i) * XST + ct * 16 + (lane & 15)];
                        pacc[tt] = __builtin_amdgcn_mfma_f32_16x16x32_bf16(a, bx, pacc[tt], 0, 0, 0);
                    }
                }
            }
        }
    }

    // final flush of the register pooling accumulator
    if (curseg >= 0) {
#pragma unroll
        for (int tt = 0; tt < 2; tt++) {
#pragma unroll
            for (int r = 0; r < 4; r++) {
                int k = (lane >> 4) * 4 + r;
                int c = (wv * 2 + tt) * 16 + (lane & 15);
                atomicAdd(&stg[((size_t)curseg * KK + k) * CCH + c], pacc[tt][r]);
            }
        }
    }
}

// merged: blocks 0..31 reduce the 8 staged out-copies; block 32 computes mu + losses
__global__ __launch_bounds__(256) void k_tail(
    const float* __restrict__ ws, const float* __restrict__ active_mask,
    float* __restrict__ out, float* __restrict__ mu_out, float* __restrict__ losses)
{
    const int tid = threadIdx.x;

    if (blockIdx.x < 32) {
        int i = blockIdx.x * 256 + tid;    // [0, 8192) float4 index
        float4 r = make_float4(0.f, 0.f, 0.f, 0.f);
#pragma unroll
        for (int c = 0; c < NST; c++) {
            float4 a = ((const float4*)(ws + ST_BASE + (size_t)c * ST_SZ))[i];
            r.x += a.x; r.y += a.y; r.z += a.z; r.w += a.w;
        }
        ((float4*)out)[i] = r;
        return;
    }

    __shared__ float lsum[256];
    __shared__ float lpos[512];
    __shared__ float lent[1];
    __shared__ float smu[512];
    __shared__ float savg[16];
    __shared__ float red[256];

    // reduce the 64 staged copies: thread t owns addresses t, t+256, t+512 (769 addrs)
    for (int a = tid; a < 769; a += 256) {
        float acc = 0.0f;
#pragma unroll 8
        for (int c = 0; c < NRED; c++) acc += ws[REDC_BASE + c * REDC_STRIDE + a];
        if (a < 256) lsum[a] = acc;
        else if (a < 768) lpos[a - 256] = acc;
        else lent[0] = acc;
    }
    __syncthreads();

    if (tid < 16) {
        float a = 0.0f;
#pragma unroll
        for (int b = 0; b < 16; b++) a += lsum[b * 16 + tid];
        savg[tid] = a / (float)NN;
    }
    for (int i = tid; i < 512; i += 256) {
        int sk = i >> 1;   // b*16+k
        float v = lpos[i] / (lsum[sk] + EPSF);
        smu[i] = v;
        mu_out[i] = v;
    }
    __syncthreads();

    float rep = 0.0f;
    for (int t = tid; t < 4096; t += 256) {
        int b = t >> 8, i = (t >> 4) & 15, j = t & 15;
        if (i != j) {
            float dx = smu[b * 32 + i * 2]     - smu[b * 32 + j * 2];
            float dy = smu[b * 32 + i * 2 + 1] - smu[b * 32 + j * 2 + 1];
            rep += 1.0f / (dx * dx + dy * dy + 1.0f);
        }
    }
    red[tid] = rep;
    __syncthreads();
    for (int st = 128; st > 0; st >>= 1) {
        if (tid < st) red[tid] += red[tid + st];
        __syncthreads();
    }

    if (tid == 0) {
        const float p = 1.0f / 16.0f;
        float separation = red[0] / (float)(16 * 15);
        float entropy = -lent[0] / (float)NN;
        float diversity = 0.f, pruning = 0.f, amsum = 0.f, collapse = 0.f, mean = 0.f;
        for (int k = 0; k < 16; k++) {
            float a = savg[k];
            diversity += p * logf(p / (a + EPSF));
            pruning += fabsf(a * (1.0f - active_mask[k]));
            amsum += active_mask[k];
            collapse += (a - p) * (a - p);
            mean += a;
        }
        pruning /= 16.0f;
        mean /= 16.0f;
        float var = 0.f;
        for (int k = 0; k < 16; k++) { float d = savg[k] - mean; var += d * d; }
        float balance = sqrtf(var / 16.0f);
        float sparsity = (amsum / 16.0f) * 0.01f;
        collapse *= 2.0f;
        losses[0] = entropy;   losses[1] = diversity; losses[2] = 0.0f;
        losses[3] = pruning;   losses[4] = sparsity;  losses[5] = 0.0f;
        losses[6] = collapse;  losses[7] = balance;   losses[8] = separation;
    }
}

extern "C" void kernel_launch(void* const* d_in, const int* in_sizes, int n_in,
                              void* d_out, int out_size, void* d_ws, size_t ws_size,
                              hipStream_t stream) {
    const float* x       = (const float*)d_in[0];
    const void*  batch   = d_in[1];
    const float* pos     = (const float*)d_in[2];
    const float* gumbel  = (const float*)d_in[3];
    const float* W1      = (const float*)d_in[4];
    const float* b1      = (const float*)d_in[5];
    const float* W2      = (const float*)d_in[6];
    const float* b2      = (const float*)d_in[7];
    const float* scaling = (const float*)d_in[8];
    const float* am      = (const float*)d_in[9];

    float* out      = (float*)d_out;
    float* s_sec    = out + OFF_S;
    float* mu_sec   = out + OFF_MU;
    float* loss_sec = out + OFF_L;
    float* wsf      = (float*)d_ws;

    k_zero<<<1280, 256, 0, stream>>>(wsf, (const int*)batch);
    k_fused<<<NN / 256, 256, 0, stream>>>(x, batch, pos, gumbel, W1, b1, W2, b2,
                                          scaling, am, s_sec, wsf);
    k_tail<<<33, 256, 0, stream>>>(wsf, am, out, mu_sec, loss_sec);
}